// Round 2
// baseline (1120.235 us; speedup 1.0000x reference)
//
#include <hip/hip_runtime.h>

typedef float f32x4 __attribute__((ext_vector_type(4)));
typedef short bf16x8 __attribute__((ext_vector_type(8)));
typedef unsigned short ushort_t;
typedef unsigned int uint_t;

// ---------------- Threefry-2x32 (20 rounds), exact JAX semantics (verified r1) ----------------
__device__ __forceinline__ unsigned rotl32(unsigned x, unsigned r){ return (x << r) | (x >> (32u - r)); }

__device__ __forceinline__ void tf2x32(unsigned k0, unsigned k1, unsigned c0, unsigned c1,
                                       unsigned &o0, unsigned &o1){
  unsigned ks2 = k0 ^ k1 ^ 0x1BD11BDAu;
  unsigned x0 = c0 + k0, x1 = c1 + k1;
#define TFR(r) { x0 += x1; x1 = rotl32(x1, r); x1 ^= x0; }
  TFR(13) TFR(15) TFR(26) TFR(6)
  x0 += k1;  x1 += ks2 + 1u;
  TFR(17) TFR(29) TFR(16) TFR(24)
  x0 += ks2; x1 += k0 + 2u;
  TFR(13) TFR(15) TFR(26) TFR(6)
  x0 += k0;  x1 += k1 + 3u;
  TFR(17) TFR(29) TFR(16) TFR(24)
  x0 += k1;  x1 += ks2 + 4u;
  TFR(13) TFR(15) TFR(26) TFR(6)
  x0 += ks2; x1 += k0 + 5u;
#undef TFR
  o0 = x0; o1 = x1;
}

__device__ __forceinline__ float bits_to_u01(unsigned bits){
  return __uint_as_float((bits >> 9) | 0x3f800000u) - 1.0f;
}

// XLA ErfInv32 (Giles polynomial) — verified r1
__device__ __forceinline__ float erfinv_f(float x){
  float w = -log1pf(-x * x);
  float p;
  if (w < 5.0f){
    w -= 2.5f;
    p = 2.81022636e-08f;
    p = 3.43273939e-07f + p * w;
    p = -3.5233877e-06f + p * w;
    p = -4.39150654e-06f + p * w;
    p = 0.00021858087f + p * w;
    p = -0.00125372503f + p * w;
    p = -0.00417768164f + p * w;
    p = 0.246640727f + p * w;
    p = 1.50140941f + p * w;
  } else {
    w = sqrtf(w) - 3.0f;
    p = -0.000200214257f;
    p = 0.000100950558f + p * w;
    p = 0.00134934322f + p * w;
    p = -0.00367342844f + p * w;
    p = 0.00573950773f + p * w;
    p = -0.0076224613f + p * w;
    p = 0.00943887047f + p * w;
    p = 1.00167406f + p * w;
    p = 2.83297682f + p * w;
  }
  return p * x;
}

__device__ __forceinline__ ushort_t f2bf(float f){
  unsigned u = __float_as_uint(f);
  unsigned r = u + 0x7fffu + ((u >> 16) & 1u);
  return (ushort_t)(r >> 16);
}
__device__ __forceinline__ float bf2f(ushort_t h){ return __uint_as_float(((unsigned)h) << 16); }

// normal draw for element e of group g under step-key (sk0,sk1)
__device__ __forceinline__ float norm_draw(unsigned sk0, unsigned sk1, unsigned g, unsigned e){
  unsigned gk0, gk1, b0, b1;
  tf2x32(sk0, sk1, 0u, g, gk0, gk1);
  tf2x32(gk0, gk1, 0u, e, b0, b1);
  unsigned bits = b0 ^ b1;
  float u01 = bits_to_u01(bits);
  const float LO = __uint_as_float(0xBF7FFFFFu);
  float u = u01 * 2.0f + LO;
  u = fmaxf(LO, u);
  return 1.41421356237f * erfinv_f(u);
}

// ---------------- geometry ----------------
// B=32768, OBS_LEN=8, IN_DIM=2, HID=128, 4H=512, PRED_LEN=12
constexpr int BT = 64;       // batch rows per block
constexpr int PITCH = 168;   // LDS row pitch (elems): 128 h + x0,x1,1.0 + zeros + pad (336B rows, 16B aligned)
constexpr int WROW_E = 160;  // extended weight row length (K=160)

// ws element offsets (bytes)
// whh0e @0 (163840), wih1e @163840, whh1b @327680 (131072), dwhide @458752 (12*163840),
// dwout @2424832 (24576), dbout @2449408 (192), maskT @2449600 (4194304)

// ---------------- fused prep: mask + sampling + weight build + KL ----------------
__global__ void prep_all(
    const float* __restrict__ wih0,  const float* __restrict__ whh0,
    const float* __restrict__ bih0,  const float* __restrict__ bhh0,
    const float* __restrict__ wih1,  const float* __restrict__ whh1,
    const float* __restrict__ bih1,  const float* __restrict__ bhh1,
    const float* __restrict__ din_wmu, const float* __restrict__ din_wrho,
    const float* __restrict__ din_bmu, const float* __restrict__ din_brho,
    const float* __restrict__ dhid_wmu, const float* __restrict__ dhid_wrho,
    const float* __restrict__ dhid_bmu, const float* __restrict__ dhid_brho,
    const float* __restrict__ out_wmu, const float* __restrict__ out_wrho,
    const float* __restrict__ out_bmu, const float* __restrict__ out_brho,
    ushort_t* __restrict__ whh0e, ushort_t* __restrict__ wih1e, ushort_t* __restrict__ whh1b,
    ushort_t* __restrict__ dwhide, float* __restrict__ dwout, float* __restrict__ dbout,
    unsigned* __restrict__ maskT, float* __restrict__ out){
  const int blk = blockIdx.x, tid = threadIdx.x;

  if (blk < 4096){
    // ---- dropout mask, transposed layout: word = t*131072 + h*1024 + (b>>5), bit b&31 ----
    unsigned w = blk * 256u + tid;
    unsigned t = w >> 17, h = (w >> 10) & 127u, bw = w & 1023u;
    unsigned word = 0;
    #pragma unroll 4
    for (int i = 0; i < 32; ++i){
      unsigned ctr = (bw * 32u + i) * 1024u + t * 128u + h;  // JAX flat idx b*1024+t*128+h
      unsigned o0, o1;
      tf2x32(0u, 1u, 0u, ctr, o0, o1);
      float u = bits_to_u01(o0 ^ o1);
      word |= (u < 0.9f ? 1u : 0u) << i;
    }
    maskT[w] = word;
  } else if (blk < 4992){
    // ---- encoder weight build ----
    int idx = (blk - 4096) * 256 + tid;   // < 229376 exactly
    if (idx < 81920){
      int row = idx / 160, col = idx - row * 160;
      float v;
      if (col < 128)       v = whh0[row * 128 + col];
      else if (col == 128) v = wih0[row * 2];
      else if (col == 129) v = wih0[row * 2 + 1];
      else if (col == 130) v = bih0[row] + bhh0[row];
      else                 v = 0.0f;
      whh0e[idx] = f2bf(v);
    } else if (idx < 163840){
      int j = idx - 81920;
      int row = j / 160, col = j - row * 160;
      float v;
      if (col < 128)       v = wih1[row * 128 + col];
      else if (col == 130) v = bih1[row] + bhh1[row];
      else                 v = 0.0f;
      wih1e[j] = f2bf(v);
    } else {
      int j = idx - 163840;   // < 65536
      whh1b[j] = f2bf(whh1[j]);
    }
  } else if (blk < 8857){
    // ---- decoder sampled weights (key(2), partitionable threefry) ----
    int idx = (blk - 4992) * 256 + tid;
    if (idx >= 12 * 82436) return;
    int s = idx / 82436, r = idx - s * 82436;
    unsigned sk0, sk1;
    tf2x32(0u, 2u, 0u, (unsigned)s, sk0, sk1);  // step_keys = split(key(2), 12)
    if (r < 81920){
      int row = r / 160, col = r - row * 160;
      float v;
      if (col < 128){
        unsigned e = (unsigned)(row * 128 + col);
        v = dhid_wmu[e] + log1pf(expf(dhid_wrho[e])) * norm_draw(sk0, sk1, 2u, e);
      } else if (col == 128){
        unsigned e = (unsigned)(row * 2);
        v = din_wmu[e] + log1pf(expf(din_wrho[e])) * norm_draw(sk0, sk1, 0u, e);
      } else if (col == 129){
        unsigned e = (unsigned)(row * 2 + 1);
        v = din_wmu[e] + log1pf(expf(din_wrho[e])) * norm_draw(sk0, sk1, 0u, e);
      } else if (col == 130){
        unsigned e = (unsigned)row;
        float v1 = din_bmu[e]  + log1pf(expf(din_brho[e]))  * norm_draw(sk0, sk1, 1u, e);
        float v2 = dhid_bmu[e] + log1pf(expf(dhid_brho[e])) * norm_draw(sk0, sk1, 3u, e);
        v = v1 + v2;
      } else v = 0.0f;
      dwhide[s * 81920 + r] = f2bf(v);
    } else if (r < 82432){
      unsigned e = (unsigned)(r - 81920);
      dwout[s * 512 + e] = out_wmu[e] + log1pf(expf(out_wrho[e])) * norm_draw(sk0, sk1, 4u, e);
    } else {
      unsigned e = (unsigned)(r - 82432);
      dbout[s * 4 + e] = out_bmu[e] + log1pf(expf(out_brho[e])) * norm_draw(sk0, sk1, 5u, e);
    }
  } else {
    // ---- KL (single block) ----
    __shared__ float red[256];
    float s = 0.f;
    auto term = [](float mu, float rho){
      float stdv = log1pf(expf(rho));
      return logf(0.1f / stdv) + (stdv * stdv + mu * mu) * 50.0f - 0.5f;
    };
    for (int i = tid; i < 1024;  i += 256) s += term(din_wmu[i], din_wrho[i]);
    for (int i = tid; i < 512;   i += 256) s += term(din_bmu[i], din_brho[i]);
    for (int i = tid; i < 65536; i += 256) s += term(dhid_wmu[i], dhid_wrho[i]);
    for (int i = tid; i < 512;   i += 256) s += term(dhid_bmu[i], dhid_brho[i]);
    for (int i = tid; i < 512;   i += 256) s += term(out_wmu[i], out_wrho[i]);
    if (tid < 4) s += term(out_bmu[tid], out_brho[tid]);
    red[tid] = s;
    __syncthreads();
    for (int off = 128; off > 0; off >>= 1){
      if (tid < off) red[tid] += red[tid + off];
      __syncthreads();
    }
    if (tid == 0) out[1572864] = red[0];
  }
}

// ---------------- activation: combined-rcp LSTM element (8 transcendentals) ----------------
__device__ __forceinline__ float lstm_elem(float gi, float gf, float gg, float go, float& c){
  float sf = __builtin_amdgcn_rcpf(1.0f + __expf(-gf));
  float Ei = __expf(-gi);
  float Eg = __expf(2.0f * gg);
  float itanh = (Eg - 1.0f) * __builtin_amdgcn_rcpf((1.0f + Ei) * (Eg + 1.0f));
  float cn = sf * c + itanh;
  c = cn;
  float Eo = __expf(-go);
  float Ec = __expf(2.0f * cn);
  return (Ec - 1.0f) * __builtin_amdgcn_rcpf((1.0f + Eo) * (Ec + 1.0f));
}

// ---------------- GEMM: acc[g][wc][m] += H(64 x K) @ W(512 x K)^T, chunk-rolled B (depth 3) ----------------
template<int NKI, int WROW>
__device__ __forceinline__ void gemm_T(const ushort_t* __restrict__ H,
                                       const ushort_t* __restrict__ W,
                                       int wv, int lx, int lg, f32x4 (&acc)[4][2][4]){
  const ushort_t* wp = W + (32 * wv + lx) * WROW + 8 * lg;
  const ushort_t* hp = H + lx * PITCH + 8 * lg;
  bf16x8 B[3][4];
  #pragma unroll
  for (int c = 0; c < 3; ++c){
    int ki = c >> 1, wc = c & 1;
    #pragma unroll
    for (int g = 0; g < 4; ++g)
      B[c][g] = *(const bf16x8*)(wp + (128 * g + 16 * wc) * WROW + 32 * ki);
  }
  bf16x8 a[4];
  #pragma unroll
  for (int c = 0; c < 2 * NKI; ++c){
    int ki = c >> 1, wc = c & 1;
    if (wc == 0){
      #pragma unroll
      for (int m = 0; m < 4; ++m)
        a[m] = *(const bf16x8*)(hp + 16 * m * PITCH + 32 * ki);
    }
    #pragma unroll
    for (int g = 0; g < 4; ++g)
      #pragma unroll
      for (int m = 0; m < 4; ++m)
        acc[g][wc][m] = __builtin_amdgcn_mfma_f32_16x16x32_bf16(a[m], B[c % 3][g], acc[g][wc][m], 0, 0, 0);
    if (c + 3 < 2 * NKI){
      int ki2 = (c + 3) >> 1, wc2 = (c + 3) & 1;
      #pragma unroll
      for (int g = 0; g < 4; ++g)
        B[c % 3][g] = *(const bf16x8*)(wp + (128 * g + 16 * wc2) * WROW + 32 * ki2);
    }
  }
}

__device__ __forceinline__ float cp_lo(unsigned w){ return __uint_as_float(w << 16); }
__device__ __forceinline__ float cp_hi(unsigned w){ return __uint_as_float(w & 0xFFFF0000u); }
__device__ __forceinline__ unsigned cp_pack(float lo, float hi){
  return (__float_as_uint(hi) & 0xFFFF0000u) | (__float_as_uint(lo) >> 16);
}

// ---------------- main fused kernel: 256 thr (4 waves), BT=64, grid 512 ----------------
__global__ __launch_bounds__(256, 2) void lstm_main(
    const float* __restrict__ obs,        // [32768][8][2]
    const ushort_t* __restrict__ whh0e,   // [512][160]
    const ushort_t* __restrict__ wih1e,   // [512][160]
    const ushort_t* __restrict__ whh1b,   // [512][128]
    const ushort_t* __restrict__ dwhide,  // [12][512][160]
    const float* __restrict__ dwout,      // [12][4][128]
    const float* __restrict__ dbout,      // [12][4]
    const unsigned* __restrict__ maskT,   // [8][128][1024]
    float* __restrict__ out){
  __shared__ __align__(16) ushort_t sm[3 * BT * PITCH];   // 64512 B
  ushort_t* H0 = sm;
  ushort_t* HD = sm + BT * PITCH;
  ushort_t* H1 = sm + 2 * BT * PITCH;

  const int tid = threadIdx.x;
  const int wv = tid >> 6;       // 0..3
  const int l  = tid & 63;
  const int lx = l & 15;
  const int lg = l >> 4;
  const int b0 = blockIdx.x * BT;

  // ---- init: zero all LDS, then const cols ----
  {
    uint_t* p = (uint_t*)sm;
    for (int i = tid; i < 3 * BT * PITCH / 2; i += 256) p[i] = 0;
  }
  __syncthreads();
  if (tid < 192){ // col 130 = 1.0 for all 3 buffers
    int buf = tid / 64, r = tid & 63;
    sm[buf * BT * PITCH + r * PITCH + 130] = (ushort_t)0x3F80;
  }
  if (tid < 128){ // x_0 into H0 cols 128/129
    int r = tid >> 1, c = tid & 1;
    H0[r * PITCH + 128 + c] = f2bf(obs[(b0 + r) * 16 + c]);
  }
  unsigned c0p[16], c1p[16];
  #pragma unroll
  for (int i = 0; i < 16; ++i){ c0p[i] = 0; c1p[i] = 0; }
  __syncthreads();

  f32x4 acc[4][2][4];
  const f32x4 zero4 = {0.f, 0.f, 0.f, 0.f};
#define ZERO_ACC() { _Pragma("unroll") for (int g=0;g<4;++g) _Pragma("unroll") for (int wc=0;wc<2;++wc) _Pragma("unroll") for (int m=0;m<4;++m) acc[g][wc][m]=zero4; }

  // ================= encoder: 8 steps =================
  for (int t = 0; t < 8; ++t){
    // ---- layer 0: gates = [h0 | x | 1] @ whh0e^T ----
    ZERO_ACC();
    gemm_T<5, WROW_E>(H0, whh0e, wv, lx, lg, acc);
    __syncthreads();
    {
      uint2 mk[2];
      #pragma unroll
      for (int wc = 0; wc < 2; ++wc){
        int hj = 32 * wv + 16 * wc + lx;
        mk[wc] = *(const uint2*)(maskT + (unsigned)t * 131072u + (unsigned)hj * 1024u + (unsigned)(blockIdx.x * 2));
      }
      #pragma unroll
      for (int wc = 0; wc < 2; ++wc){
        int hj = 32 * wv + 16 * wc + lx;
        #pragma unroll
        for (int m = 0; m < 4; ++m){
          unsigned mbits = (m & 2) ? mk[wc].y : mk[wc].x;
          #pragma unroll
          for (int ep = 0; ep < 2; ++ep){
            unsigned cw = c0p[wc * 8 + m * 2 + ep];
            float cv0 = cp_lo(cw), cv1 = cp_hi(cw);
            int e0 = 2 * ep, r0 = 16 * m + 4 * lg + e0;
            float h0v = lstm_elem(acc[0][wc][m][e0], acc[1][wc][m][e0], acc[2][wc][m][e0], acc[3][wc][m][e0], cv0);
            float h1v = lstm_elem(acc[0][wc][m][e0+1], acc[1][wc][m][e0+1], acc[2][wc][m][e0+1], acc[3][wc][m][e0+1], cv1);
            c0p[wc * 8 + m * 2 + ep] = cp_pack(cv0, cv1);
            H0[r0 * PITCH + hj] = f2bf(h0v);
            H0[(r0 + 1) * PITCH + hj] = f2bf(h1v);
            unsigned k0 = (mbits >> (r0 & 31)) & 1u;
            unsigned k1 = (mbits >> ((r0 + 1) & 31)) & 1u;
            HD[r0 * PITCH + hj] = k0 ? f2bf(h0v * (1.0f / 0.9f)) : (ushort_t)0;
            HD[(r0 + 1) * PITCH + hj] = k1 ? f2bf(h1v * (1.0f / 0.9f)) : (ushort_t)0;
          }
        }
      }
    }
    __syncthreads();
    // ---- layer 1: gates = [hd | 0 0 1] @ wih1e^T + h1 @ whh1^T ----
    ZERO_ACC();
    gemm_T<5, WROW_E>(HD, wih1e, wv, lx, lg, acc);
    gemm_T<4, 128>(H1, whh1b, wv, lx, lg, acc);
    __syncthreads();
    #pragma unroll
    for (int wc = 0; wc < 2; ++wc){
      int hj = 32 * wv + 16 * wc + lx;
      #pragma unroll
      for (int m = 0; m < 4; ++m){
        #pragma unroll
        for (int ep = 0; ep < 2; ++ep){
          unsigned cw = c1p[wc * 8 + m * 2 + ep];
          float cv0 = cp_lo(cw), cv1 = cp_hi(cw);
          int e0 = 2 * ep, r0 = 16 * m + 4 * lg + e0;
          float h0v = lstm_elem(acc[0][wc][m][e0], acc[1][wc][m][e0], acc[2][wc][m][e0], acc[3][wc][m][e0], cv0);
          float h1v = lstm_elem(acc[0][wc][m][e0+1], acc[1][wc][m][e0+1], acc[2][wc][m][e0+1], acc[3][wc][m][e0+1], cv1);
          c1p[wc * 8 + m * 2 + ep] = cp_pack(cv0, cv1);
          H1[r0 * PITCH + hj] = f2bf(h0v);
          H1[(r0 + 1) * PITCH + hj] = f2bf(h1v);
        }
      }
    }
    // x_{t+1} into H0 cols 128/129
    if (t < 7 && tid < 128){
      int r = tid >> 1, c = tid & 1;
      H0[r * PITCH + 128 + c] = f2bf(obs[(b0 + r) * 16 + 2 * (t + 1) + c]);
    }
    __syncthreads();
  }

  // decoder initial x = obs[:, 7, :] into H1 cols 128/129
  if (tid < 128){
    int r = tid >> 1, c = tid & 1;
    H1[r * PITCH + 128 + c] = f2bf(obs[(b0 + r) * 16 + 14 + c]);
  }
  __syncthreads();

  // ================= decoder: 12 steps =================
  for (int s = 0; s < 12; ++s){
    ZERO_ACC();
    gemm_T<5, WROW_E>(H1, dwhide + s * 81920, wv, lx, lg, acc);
    __syncthreads();
    #pragma unroll
    for (int wc = 0; wc < 2; ++wc){
      int hj = 32 * wv + 16 * wc + lx;
      #pragma unroll
      for (int m = 0; m < 4; ++m){
        #pragma unroll
        for (int ep = 0; ep < 2; ++ep){
          unsigned cw = c1p[wc * 8 + m * 2 + ep];
          float cv0 = cp_lo(cw), cv1 = cp_hi(cw);
          int e0 = 2 * ep, r0 = 16 * m + 4 * lg + e0;
          float h0v = lstm_elem(acc[0][wc][m][e0], acc[1][wc][m][e0], acc[2][wc][m][e0], acc[3][wc][m][e0], cv0);
          float h1v = lstm_elem(acc[0][wc][m][e0+1], acc[1][wc][m][e0+1], acc[2][wc][m][e0+1], acc[3][wc][m][e0+1], cv1);
          c1p[wc * 8 + m * 2 + ep] = cp_pack(cv0, cv1);
          H1[r0 * PITCH + hj] = f2bf(h0v);
          H1[(r0 + 1) * PITCH + hj] = f2bf(h1v);
        }
      }
    }
    __syncthreads();
    // ---- out head: 64 rows x 4 outs = 256 threads ----
    {
      int r = tid >> 2, o = tid & 3;
      const float* wo = dwout + s * 512 + o * 128;
      float sum = dbout[s * 4 + o];
      const ushort_t* hrow = H1 + r * PITCH;
      #pragma unroll
      for (int k = 0; k < 128; k += 8){
        bf16x8 hv = *(const bf16x8*)(hrow + k);
        f32x4 wa = *(const f32x4*)(wo + k);
        f32x4 wb = *(const f32x4*)(wo + k + 4);
        sum += bf2f((ushort_t)hv[0]) * wa[0] + bf2f((ushort_t)hv[1]) * wa[1]
             + bf2f((ushort_t)hv[2]) * wa[2] + bf2f((ushort_t)hv[3]) * wa[3]
             + bf2f((ushort_t)hv[4]) * wb[0] + bf2f((ushort_t)hv[5]) * wb[1]
             + bf2f((ushort_t)hv[6]) * wb[2] + bf2f((ushort_t)hv[7]) * wb[3];
      }
      int gb = b0 + r;
      if (o < 2){
        out[gb * 24 + s * 2 + o] = sum;
        H1[r * PITCH + 128 + o] = f2bf(sum);   // mu feedback
      } else {
        out[786432 + gb * 24 + s * 2 + (o - 2)] = fminf(fmaxf(sum, -4.0f), 2.0f);
      }
    }
    __syncthreads();
  }
}

// ---------------- launch ----------------
extern "C" void kernel_launch(void* const* d_in, const int* in_sizes, int n_in,
                              void* d_out, int out_size, void* d_ws, size_t ws_size,
                              hipStream_t stream){
  (void)in_sizes; (void)n_in; (void)out_size; (void)ws_size;
  const float* obs   = (const float*)d_in[0];
  const float* wih0  = (const float*)d_in[1];
  const float* whh0  = (const float*)d_in[2];
  const float* bih0  = (const float*)d_in[3];
  const float* bhh0  = (const float*)d_in[4];
  const float* wih1  = (const float*)d_in[5];
  const float* whh1  = (const float*)d_in[6];
  const float* bih1  = (const float*)d_in[7];
  const float* bhh1  = (const float*)d_in[8];
  const float* din_wmu  = (const float*)d_in[9];
  const float* din_wrho = (const float*)d_in[10];
  const float* din_bmu  = (const float*)d_in[11];
  const float* din_brho = (const float*)d_in[12];
  const float* dhid_wmu  = (const float*)d_in[13];
  const float* dhid_wrho = (const float*)d_in[14];
  const float* dhid_bmu  = (const float*)d_in[15];
  const float* dhid_brho = (const float*)d_in[16];
  const float* out_wmu  = (const float*)d_in[17];
  const float* out_wrho = (const float*)d_in[18];
  const float* out_bmu  = (const float*)d_in[19];
  const float* out_brho = (const float*)d_in[20];

  char* wsb = (char*)d_ws;
  ushort_t* whh0e  = (ushort_t*)(wsb + 0);
  ushort_t* wih1e  = (ushort_t*)(wsb + 163840);
  ushort_t* whh1b  = (ushort_t*)(wsb + 327680);
  ushort_t* dwhide = (ushort_t*)(wsb + 458752);
  float*    dwout  = (float*)(wsb + 2424832);
  float*    dbout  = (float*)(wsb + 2449408);
  unsigned* maskT  = (unsigned*)(wsb + 2449600);

  prep_all<<<8858, 256, 0, stream>>>(
      wih0, whh0, bih0, bhh0, wih1, whh1, bih1, bhh1,
      din_wmu, din_wrho, din_bmu, din_brho,
      dhid_wmu, dhid_wrho, dhid_bmu, dhid_brho,
      out_wmu, out_wrho, out_bmu, out_brho,
      whh0e, wih1e, whh1b, dwhide, dwout, dbout, maskT, (float*)d_out);

  lstm_main<<<512, 256, 0, stream>>>(obs, whh0e, wih1e, whh1b, dwhide, dwout, dbout,
                                     maskT, (float*)d_out);
}